// Round 1
// baseline (49.833 us; speedup 1.0000x reference)
//
#include <hip/hip_runtime.h>

// out[b,s,d] = x[b,s,d] + pe[s,d]
//   d < 512 : pe = sin(s * 10000^(-2d/1024))
//   d >= 512: pe = cos(s * 10000^(-(2*(d-512)+1)/1024))
// B=8, S=4096, D=1024, fp32. Memory-bound: 256 MiB traffic, ~43us floor.
// One block per s-row; thread owns a float4 of d; pe computed once/thread,
// reused across the 8 batch rows (amortizes trig 8x).

__global__ __launch_bounds__(256) void pe_add_kernel(const float4* __restrict__ x,
                                                     float4* __restrict__ out) {
    constexpr int S = 4096;
    constexpr int B = 8;
    constexpr int ROW4 = 1024 / 4;        // float4s per row = 256

    const int s = blockIdx.x;             // 0..4095
    const int t = threadIdx.x;            // 0..255
    const int d0 = t * 4;

    const float pos = (float)s;
    const float NLOG2_10000_OVER_D = -13.287712379549449f * (1.0f / 1024.0f);

    // 512 % 4 == 0 -> all 4 lanes of this thread are on the same side.
    float pe[4];
    if (d0 < 512) {
        #pragma unroll
        for (int j = 0; j < 4; ++j) {
            const float k = 2.0f * (float)(d0 + j);
            const float invfreq = exp2f(k * NLOG2_10000_OVER_D);
            pe[j] = sinf(pos * invfreq);
        }
    } else {
        #pragma unroll
        for (int j = 0; j < 4; ++j) {
            const float k = 2.0f * (float)(d0 - 512 + j) + 1.0f;
            const float invfreq = exp2f(k * NLOG2_10000_OVER_D);
            pe[j] = cosf(pos * invfreq);
        }
    }

    const int rowbase = s * ROW4 + t;
    #pragma unroll
    for (int b = 0; b < B; ++b) {
        const int idx = b * (S * ROW4) + rowbase;
        float4 v = x[idx];
        v.x += pe[0];
        v.y += pe[1];
        v.z += pe[2];
        v.w += pe[3];
        out[idx] = v;
    }
}

extern "C" void kernel_launch(void* const* d_in, const int* in_sizes, int n_in,
                              void* d_out, int out_size, void* d_ws, size_t ws_size,
                              hipStream_t stream) {
    const float4* x = (const float4*)d_in[0];
    float4* out = (float4*)d_out;
    // grid: one block per s-row
    pe_add_kernel<<<dim3(4096), dim3(256), 0, stream>>>(x, out);
}